// Round 1
// baseline (612.464 us; speedup 1.0000x reference)
//
#include <hip/hip_runtime.h>
#include <math.h>

#define BATCH 8
#define NPTS 2048
#define MPTS 2048

// Persistent state (re-initialized every kernel_launch -> deterministic).
__device__ float g_remainl[BATCH*NPTS];
__device__ float g_s[BATCH*NPTS];
__device__ float g_remainr[BATCH*MPTS];
__device__ float g_colsum[BATCH*MPTS];
__device__ float g_p[BATCH*MPTS];       // remainr_old * ratio
__device__ float g_cost;

__global__ __launch_bounds__(256) void k_init() {
  int i = blockIdx.x*256 + threadIdx.x;   // 64 blocks x 256 = 16384
  g_remainl[i] = 1.0f;   // factorl = max(n,m)/n = 1
  g_remainr[i] = 1.0f;   // factorr = 1
  g_colsum[i]  = 0.0f;
  if (i == 0) g_cost = 0.0f;
}

// Phase A: per row n compute rowsum = sum_m exp(level*d2)*remainr[m],
// s_n = remainl[n]/(rowsum+1e-9); accumulate colsum[m] += w_pre*s_n.
// w row kept in 32 VGPRs per lane (no recompute between the two uses).
__global__ __launch_bounds__(256) void k_rows_a(const float* __restrict__ gen,
                                                const float* __restrict__ gt,
                                                float level) {
  const int blk   = blockIdx.x;     // 512 blocks: 64 chunks x 8 batches
  const int b     = blk >> 6;
  const int chunk = blk & 63;       // 32 rows per chunk
  const int t     = threadIdx.x;
  const int wave  = t >> 6;
  const int lane  = t & 63;
  __shared__ float s_gt[MPTS*3];    // 24 KB
  __shared__ float s_rr[MPTS];      // 8 KB
  __shared__ float s_col[4][MPTS];  // 32 KB, per-wave colsum (no LDS atomics)
  for (int i = t; i < MPTS*3; i += 256) s_gt[i] = gt[b*MPTS*3 + i];
  for (int i = t; i < MPTS; i += 256) {
    s_rr[i] = g_remainr[b*MPTS + i];
    s_col[0][i] = 0.f; s_col[1][i] = 0.f; s_col[2][i] = 0.f; s_col[3][i] = 0.f;
  }
  __syncthreads();
  for (int r = 0; r < 8; ++r) {     // 8 rows per wave
    const int n = chunk*32 + wave*8 + r;
    const float gx = gen[(b*NPTS+n)*3+0];
    const float gy = gen[(b*NPTS+n)*3+1];
    const float gz = gen[(b*NPTS+n)*3+2];
    float w[32];
    float rowsum = 0.f;
    #pragma unroll
    for (int k = 0; k < 32; ++k) {
      const int m = lane + 64*k;
      const float dx = gx - s_gt[m*3+0];
      const float dy = gy - s_gt[m*3+1];
      const float dz = gz - s_gt[m*3+2];
      const float d2 = dx*dx + dy*dy + dz*dz;
      const float wv = __expf(level*d2) * s_rr[m];
      w[k] = wv;
      rowsum += wv;
    }
    #pragma unroll
    for (int off = 32; off > 0; off >>= 1) rowsum += __shfl_down(rowsum, off);
    rowsum = __shfl(rowsum, 0);
    const float sc = g_remainl[b*NPTS+n] / (rowsum + 1e-9f);
    if (lane == 0) g_s[b*NPTS+n] = sc;
    #pragma unroll
    for (int k = 0; k < 32; ++k) {
      const int m = lane + 64*k;
      s_col[wave][m] += w[k]*sc;
    }
  }
  __syncthreads();
  for (int i = t; i < MPTS; i += 256) {
    const float v = s_col[0][i] + s_col[1][i] + s_col[2][i] + s_col[3][i];
    atomicAdd(&g_colsum[b*MPTS+i], v);
  }
}

// Phase B: column ratio, p = rr_old*ratio, remainr update, re-zero colsum.
__global__ __launch_bounds__(256) void k_cols() {
  const int i = blockIdx.x*256 + threadIdx.x;   // 64 blocks x 256 = 16384
  const float cs = g_colsum[i];
  const float rr = g_remainr[i];
  const float ratio = fminf(rr / (cs + 1e-9f), 1.0f);
  g_p[i]       = rr * ratio;
  g_remainr[i] = fmaxf(rr - cs*ratio, 0.0f);
  g_colsum[i]  = 0.0f;   // ready for next level's atomics
}

// Phase C: recompute w_final = exp(level*d2)*p[m]*s_n; accumulate cost
// (+= w*sqrt(d2)) and remainl update.
__global__ __launch_bounds__(256) void k_rows_b(const float* __restrict__ gen,
                                                const float* __restrict__ gt,
                                                float level) {
  const int blk   = blockIdx.x;
  const int b     = blk >> 6;
  const int chunk = blk & 63;
  const int t     = threadIdx.x;
  const int wave  = t >> 6;
  const int lane  = t & 63;
  __shared__ float s_gt[MPTS*3];
  __shared__ float s_p[MPTS];
  __shared__ float s_cost[4];
  for (int i = t; i < MPTS*3; i += 256) s_gt[i] = gt[b*MPTS*3 + i];
  for (int i = t; i < MPTS; i += 256) s_p[i] = g_p[b*MPTS + i];
  __syncthreads();
  float costacc = 0.f;
  for (int r = 0; r < 8; ++r) {
    const int n = chunk*32 + wave*8 + r;
    const float gx = gen[(b*NPTS+n)*3+0];
    const float gy = gen[(b*NPTS+n)*3+1];
    const float gz = gen[(b*NPTS+n)*3+2];
    const float sc = g_s[b*NPTS+n];
    float rowsum2 = 0.f;
    #pragma unroll
    for (int k = 0; k < 32; ++k) {
      const int m = lane + 64*k;
      const float dx = gx - s_gt[m*3+0];
      const float dy = gy - s_gt[m*3+1];
      const float dz = gz - s_gt[m*3+2];
      const float d2 = dx*dx + dy*dy + dz*dz;
      const float wv = __expf(level*d2) * s_p[m] * sc;
      rowsum2 += wv;
      costacc += wv * sqrtf(fmaxf(d2, 1e-20f));
    }
    #pragma unroll
    for (int off = 32; off > 0; off >>= 1) rowsum2 += __shfl_down(rowsum2, off);
    if (lane == 0) {
      const int idx = b*NPTS + n;
      g_remainl[idx] = fmaxf(g_remainl[idx] - rowsum2, 0.0f);
    }
  }
  #pragma unroll
  for (int off = 32; off > 0; off >>= 1) costacc += __shfl_down(costacc, off);
  if (lane == 0) s_cost[wave] = costacc;
  __syncthreads();
  if (t == 0) atomicAdd(&g_cost, s_cost[0]+s_cost[1]+s_cost[2]+s_cost[3]);
}

__global__ void k_final(float* __restrict__ out) {
  out[0] = g_cost * (1.0f / (float)(BATCH*NPTS));
}

extern "C" void kernel_launch(void* const* d_in, const int* in_sizes, int n_in,
                              void* d_out, int out_size, void* d_ws, size_t ws_size,
                              hipStream_t stream) {
  const float* gen = (const float*)d_in[0];   // pc_gen [8,2048,3] f32
  const float* gt  = (const float*)d_in[1];   // pc_gt  [8,2048,3] f32
  float* out = (float*)d_out;

  k_init<<<64, 256, 0, stream>>>();
  const float levels[10] = {-16384.f, -4096.f, -1024.f, -256.f, -64.f,
                            -16.f, -4.f, -1.f, -0.25f, 0.f};
  for (int l = 0; l < 10; ++l) {
    k_rows_a<<<512, 256, 0, stream>>>(gen, gt, levels[l]);
    k_cols<<<64, 256, 0, stream>>>();
    k_rows_b<<<512, 256, 0, stream>>>(gen, gt, levels[l]);
  }
  k_final<<<1, 1, 0, stream>>>(out);
}

// Round 2
// 588.079 us; speedup vs baseline: 1.0415x; 1.0415x over previous
//
#include <hip/hip_runtime.h>
#include <math.h>

#define BATCH 8
#define NPTS 2048
#define MPTS 2048
#define ROWS_PER_BLK 16
#define CHUNKS (NPTS/ROWS_PER_BLK)   // 128
#define NBLK (BATCH*CHUNKS)          // 1024
#define KS (MPTS/64)                 // 32 columns per lane

// Persistent state (re-initialized every kernel_launch -> deterministic).
__device__ float  g_remainl[BATCH*NPTS];
__device__ float  g_s[BATCH*NPTS];
__device__ float  g_remainr[BATCH*MPTS];
__device__ float  g_colsum[BATCH*MPTS];
__device__ float2 g_pr[BATCH*MPTS];   // (p = rr*ratio, rr_new)
__device__ float  g_cost;

#if __has_builtin(__builtin_amdgcn_exp2f)
#define EXP2(x) __builtin_amdgcn_exp2f(x)
#else
#define EXP2(x) exp2f(x)
#endif
#if __has_builtin(__builtin_amdgcn_sqrtf)
#define FSQRT(x) __builtin_amdgcn_sqrtf(x)
#else
#define FSQRT(x) sqrtf(x)
#endif

__global__ __launch_bounds__(256) void k_init() {
  int i = blockIdx.x*256 + threadIdx.x;   // 64 x 256 = 16384
  g_remainl[i] = 1.0f;    // factorl = 1 (n == m)
  g_remainr[i] = 1.0f;
  g_colsum[i]  = 0.0f;
  if (i == 0) g_cost = 0.0f;
}

// A-part for level 0 only (remainl = remainr = 1).
__global__ __launch_bounds__(256) void k_a0(const float* __restrict__ gen,
                                            const float* __restrict__ gt,
                                            float c1) {
  const int blk = blockIdx.x, b = blk >> 7, chunk = blk & 127;
  const int t = threadIdx.x, wave = t >> 6, lane = t & 63;
  __shared__ float smem[10240];          // 40 KB exactly
  float* gtx = smem; float* gty = smem + 2048; float* gtz = smem + 4096;
  for (int i = t; i < MPTS; i += 256) {
    gtx[i] = gt[(b*MPTS+i)*3+0];
    gty[i] = gt[(b*MPTS+i)*3+1];
    gtz[i] = gt[(b*MPTS+i)*3+2];
  }
  __syncthreads();
  float w[KS], colacc[KS];
  #pragma unroll
  for (int k = 0; k < KS; ++k) colacc[k] = 0.f;
  for (int r = 0; r < 4; ++r) {
    const int n = chunk*ROWS_PER_BLK + wave*4 + r;
    const int idx = b*NPTS + n;
    const float gx = gen[idx*3+0], gy = gen[idx*3+1], gz = gen[idx*3+2];
    float rowsum = 0.f;
    #pragma unroll
    for (int k = 0; k < KS; ++k) {
      const int m = lane + 64*k;
      const float dx = gx - gtx[m], dy = gy - gty[m], dz = gz - gtz[m];
      const float d2 = dx*dx + dy*dy + dz*dz;
      const float e = EXP2(c1*d2);
      w[k] = e; rowsum += e;
    }
    #pragma unroll
    for (int off = 1; off < 64; off <<= 1) rowsum += __shfl_xor(rowsum, off);
    const float sc = 1.0f / (rowsum + 1e-9f);
    if (lane == 0) g_s[idx] = sc;
    #pragma unroll
    for (int k = 0; k < KS; ++k) colacc[k] = fmaf(w[k], sc, colacc[k]);
  }
  __syncthreads();                       // reuse smem as per-wave colsum
  float* scol = smem + wave*2048;
  #pragma unroll
  for (int k = 0; k < KS; ++k) scol[lane + 64*k] = colacc[k];
  __syncthreads();
  for (int i = t; i < MPTS; i += 256) {
    const float v = smem[i] + smem[2048+i] + smem[4096+i] + smem[6144+i];
    atomicAdd(&g_colsum[b*MPTS+i], v);
  }
}

// B: column saturation; packs (p, rr_new) for the next kernel; resets colsum.
__global__ __launch_bounds__(256) void k_cols() {
  const int i = blockIdx.x*256 + threadIdx.x;
  const float cs = g_colsum[i];
  const float rr = g_remainr[i];
  const float ratio = fminf(rr / (cs + 1e-9f), 1.0f);
  const float rrn = fmaxf(rr - cs*ratio, 0.0f);
  g_pr[i] = make_float2(rr*ratio, rrn);
  g_remainr[i] = rrn;
  g_colsum[i] = 0.0f;
}

// Fused C(level l) + A(level l+1): one d2 per element, two exps.
__global__ __launch_bounds__(256) void k_ca(const float* __restrict__ gen,
                                            const float* __restrict__ gt,
                                            float c1, float c2) {
  const int blk = blockIdx.x, b = blk >> 7, chunk = blk & 127;
  const int t = threadIdx.x, wave = t >> 6, lane = t & 63;
  __shared__ float smem[10240];          // 40 KB: gt planar 24K + pr 16K; col alias
  float* gtx = smem; float* gty = smem + 2048; float* gtz = smem + 4096;
  float2* spr = (float2*)(smem + 6144);
  for (int i = t; i < MPTS; i += 256) {
    gtx[i] = gt[(b*MPTS+i)*3+0];
    gty[i] = gt[(b*MPTS+i)*3+1];
    gtz[i] = gt[(b*MPTS+i)*3+2];
    spr[i] = g_pr[b*MPTS+i];
  }
  __syncthreads();
  float w[KS], colacc[KS];
  #pragma unroll
  for (int k = 0; k < KS; ++k) colacc[k] = 0.f;
  float costacc = 0.f;
  for (int r = 0; r < 4; ++r) {
    const int n = chunk*ROWS_PER_BLK + wave*4 + r;
    const int idx = b*NPTS + n;
    const float gx = gen[idx*3+0], gy = gen[idx*3+1], gz = gen[idx*3+2];
    const float sc = g_s[idx];
    const float rl = g_remainl[idx];
    float s1 = 0.f, s2 = 0.f, rsn = 0.f;
    #pragma unroll
    for (int k = 0; k < KS; ++k) {
      const int m = lane + 64*k;
      const float dx = gx - gtx[m], dy = gy - gty[m], dz = gz - gtz[m];
      const float d2 = dx*dx + dy*dy + dz*dz;
      const float2 pr = spr[m];
      const float e1 = EXP2(c1*d2);
      const float u  = e1*pr.x;          // exp(l*d2) * p
      s1 += u;
      s2 = fmaf(u, FSQRT(fmaxf(d2, 1e-20f)), s2);
      const float e2 = EXP2(c2*d2);
      const float wn = e2*pr.y;          // next level's pre-weight
      w[k] = wn; rsn += wn;
    }
    costacc = fmaf(sc, s2, costacc);     // lane-partial; reduced once at end
    #pragma unroll
    for (int off = 1; off < 64; off <<= 1) {
      s1  += __shfl_xor(s1, off);
      rsn += __shfl_xor(rsn, off);
    }
    const float rowsum2 = sc*s1;
    const float rl_new  = fmaxf(rl - rowsum2, 0.0f);
    const float sc_next = rl_new / (rsn + 1e-9f);
    if (lane == 0) { g_remainl[idx] = rl_new; g_s[idx] = sc_next; }
    #pragma unroll
    for (int k = 0; k < KS; ++k) colacc[k] = fmaf(w[k], sc_next, colacc[k]);
  }
  #pragma unroll
  for (int off = 1; off < 64; off <<= 1) costacc += __shfl_xor(costacc, off);
  __syncthreads();                       // all reads of gt/pr done; reuse smem
  float* scol = smem + wave*2048;
  #pragma unroll
  for (int k = 0; k < KS; ++k) scol[lane + 64*k] = colacc[k];
  if (lane == 0) smem[8192 + wave] = costacc;
  __syncthreads();
  for (int i = t; i < MPTS; i += 256) {
    const float v = smem[i] + smem[2048+i] + smem[4096+i] + smem[6144+i];
    atomicAdd(&g_colsum[b*MPTS+i], v);
  }
  if (t == 0)
    atomicAdd(&g_cost, smem[8192] + smem[8193] + smem[8194] + smem[8195]);
}

// C-part only for the final level (no remainl / next-A needed).
__global__ __launch_bounds__(256) void k_c_last(const float* __restrict__ gen,
                                                const float* __restrict__ gt,
                                                float c1) {
  const int blk = blockIdx.x, b = blk >> 7, chunk = blk & 127;
  const int t = threadIdx.x, wave = t >> 6, lane = t & 63;
  __shared__ float smem[10240];
  float* gtx = smem; float* gty = smem + 2048; float* gtz = smem + 4096;
  float2* spr = (float2*)(smem + 6144);
  for (int i = t; i < MPTS; i += 256) {
    gtx[i] = gt[(b*MPTS+i)*3+0];
    gty[i] = gt[(b*MPTS+i)*3+1];
    gtz[i] = gt[(b*MPTS+i)*3+2];
    spr[i] = g_pr[b*MPTS+i];
  }
  __syncthreads();
  float costacc = 0.f;
  for (int r = 0; r < 4; ++r) {
    const int n = chunk*ROWS_PER_BLK + wave*4 + r;
    const int idx = b*NPTS + n;
    const float gx = gen[idx*3+0], gy = gen[idx*3+1], gz = gen[idx*3+2];
    const float sc = g_s[idx];
    float s2 = 0.f;
    #pragma unroll
    for (int k = 0; k < KS; ++k) {
      const int m = lane + 64*k;
      const float dx = gx - gtx[m], dy = gy - gty[m], dz = gz - gtz[m];
      const float d2 = dx*dx + dy*dy + dz*dz;
      const float u = EXP2(c1*d2) * spr[m].x;
      s2 = fmaf(u, FSQRT(fmaxf(d2, 1e-20f)), s2);
    }
    costacc = fmaf(sc, s2, costacc);
  }
  #pragma unroll
  for (int off = 1; off < 64; off <<= 1) costacc += __shfl_xor(costacc, off);
  if (lane == 0) smem[8192 + wave] = costacc;
  __syncthreads();
  if (t == 0)
    atomicAdd(&g_cost, smem[8192] + smem[8193] + smem[8194] + smem[8195]);
}

__global__ void k_final(float* __restrict__ out) {
  out[0] = g_cost * (1.0f / (float)(BATCH*NPTS));
}

extern "C" void kernel_launch(void* const* d_in, const int* in_sizes, int n_in,
                              void* d_out, int out_size, void* d_ws, size_t ws_size,
                              hipStream_t stream) {
  const float* gen = (const float*)d_in[0];   // pc_gen [8,2048,3] f32
  const float* gt  = (const float*)d_in[1];   // pc_gt  [8,2048,3] f32
  float* out = (float*)d_out;

  const double L[10] = {-16384.0, -4096.0, -1024.0, -256.0, -64.0,
                        -16.0, -4.0, -1.0, -0.25, 0.0};
  float c[10];
  for (int i = 0; i < 10; ++i) c[i] = (float)(L[i] * 1.4426950408889634);

  k_init<<<64, 256, 0, stream>>>();
  k_a0<<<NBLK, 256, 0, stream>>>(gen, gt, c[0]);
  for (int l = 0; l < 9; ++l) {
    k_cols<<<64, 256, 0, stream>>>();
    k_ca<<<NBLK, 256, 0, stream>>>(gen, gt, c[l], c[l+1]);
  }
  k_cols<<<64, 256, 0, stream>>>();
  k_c_last<<<NBLK, 256, 0, stream>>>(gen, gt, c[9]);
  k_final<<<1, 1, 0, stream>>>(out);
}